// Round 1
// baseline (165.379 us; speedup 1.0000x reference)
//
#include <hip/hip_runtime.h>
#include <hip/hip_bf16.h>
#include <math.h>

#define NF    50            // n_frequencies
#define DSINE (4 * NF)      // 200
#define DEMB  10            // embedding dim

// ---------------------------------------------------------------------------
// Fill LDS table of base frequency / (2*pi):  base_i = 1000^(-2(i+1)/NF)
// ---------------------------------------------------------------------------
__device__ __forceinline__ void fill_freq(float* fr) {
    int tid = threadIdx.x;
    if (tid < NF) {
        float ex = (-2.0f * (float)(tid + 1) / (float)NF) * 9.965784284662087f; // log2(1000)
        fr[tid] = exp2f(ex) * 0.15915494309189535f;  // base/(2*pi): v_sin takes revolutions
    }
}

// ---------------------------------------------------------------------------
// Per-fragment contribution: sigma(emb @ w1[g] + b1[g]) . w2row
// ---------------------------------------------------------------------------
__device__ __forceinline__ float frag_contrib(
    float x0, float x1,
    const float* __restrict__ wrow,    // w1 + g*DSINE*DEMB
    const float* __restrict__ b1row,   // b1 + g*DEMB
    const float* __restrict__ w2row,   // w2 + genes_oi[col]*DEMB
    const float* __restrict__ fr)
{
    float h[DEMB];
#pragma unroll
    for (int d = 0; d < DEMB; ++d) h[d] = b1row[d];

#pragma unroll 2
    for (int i = 0; i < NF; ++i) {
        float fv = fr[i];
        // reduce to [-0.5, 0.5] revolutions; v_sin/v_cos take revolutions
        float r0 = x0 * fv; r0 -= rintf(r0);
        float r1 = x1 * fv; r1 -= rintf(r1);
        float s0 = __builtin_amdgcn_sinf(r0);
        float c0 = __builtin_amdgcn_cosf(r0);
        float s1 = __builtin_amdgcn_sinf(r1);
        float c1 = __builtin_amdgcn_cosf(r1);
        // emb layout: s = coord*2*NF + 2*i (+1 for the pi/2-shift = cos slot)
        const float* wa = wrow + (2 * i) * DEMB;                 // coord 0
        const float* wb = wrow + (2 * NF + 2 * i) * DEMB;        // coord 1
#pragma unroll
        for (int d = 0; d < DEMB; ++d) {
            h[d] += s0 * wa[d];
            h[d] += c0 * wa[DEMB + d];
            h[d] += s1 * wb[d];
            h[d] += c1 * wb[DEMB + d];
        }
    }

    float sum = 0.0f;
#pragma unroll
    for (int d = 0; d < DEMB; ++d) {
        float sg = 1.0f / (1.0f + __expf(-h[d]));
        sum += sg * w2row[d];
    }
    return sum;
}

// ---------------------------------------------------------------------------
// Kernel 0: init out with broadcast b2, zero gene histogram
// ---------------------------------------------------------------------------
__global__ void prep_k(float* __restrict__ out, const float* __restrict__ b2,
                       const int* __restrict__ genes_oi, int gene_n, int total,
                       int* __restrict__ counts, int n_genes)
{
    int i = blockIdx.x * blockDim.x + threadIdx.x;
    if (i < total) {
        int col = (int)((unsigned)i % (unsigned)gene_n);
        out[i] = b2[genes_oi[col]];
    }
    if (i < n_genes) counts[i] = 0;
}

// ---------------------------------------------------------------------------
// Kernel 1: histogram of genemapping
// ---------------------------------------------------------------------------
__global__ void hist_k(const int* __restrict__ gm, int* __restrict__ counts, int n_frag)
{
    int f = blockIdx.x * blockDim.x + threadIdx.x;
    if (f < n_frag) atomicAdd(&counts[gm[f]], 1);
}

// ---------------------------------------------------------------------------
// Kernel 2: exclusive scan (single block, n_genes <= 512)
// ---------------------------------------------------------------------------
__global__ void scan_k(const int* __restrict__ counts, int* __restrict__ offsets,
                       int* __restrict__ cursor, int n)
{
    __shared__ int buf[512];
    int tid = threadIdx.x;
    int v = (tid < n) ? counts[tid] : 0;
    buf[tid] = v;
    __syncthreads();
    for (int d = 1; d < 512; d <<= 1) {
        int t = (tid >= d) ? buf[tid - d] : 0;
        __syncthreads();
        buf[tid] += t;
        __syncthreads();
    }
    if (tid < n) {
        int incl = buf[tid];
        offsets[tid + 1] = incl;
        cursor[tid] = incl - v;   // exclusive
    }
    if (tid == 0) offsets[0] = 0;
}

// ---------------------------------------------------------------------------
// Kernel 3: scatter fragment ids into gene-sorted order
// ---------------------------------------------------------------------------
__global__ void scatter_k(const int* __restrict__ gm, int* __restrict__ cursor,
                          int* __restrict__ sorted, int n_frag)
{
    int f = blockIdx.x * blockDim.x + threadIdx.x;
    if (f < n_frag) {
        int g = gm[f];
        int pos = atomicAdd(&cursor[g], 1);
        sorted[pos] = f;
    }
}

// ---------------------------------------------------------------------------
// Kernel 4: main — one block per gene, wave-uniform w1/b1 access
// ---------------------------------------------------------------------------
__global__ __launch_bounds__(256) void frag_sorted_k(
    const float* __restrict__ coords, const float* __restrict__ w1,
    const float* __restrict__ b1, const float* __restrict__ w2,
    const int* __restrict__ lcg, const int* __restrict__ genes_oi,
    const int* __restrict__ sorted, const int* __restrict__ offsets,
    float* __restrict__ out, int gene_n)
{
    __shared__ float fr[NF];
    fill_freq(fr);
    __syncthreads();

    int g = blockIdx.x;   // uniform gene per block
    const float* wrow  = w1 + (size_t)g * (DSINE * DEMB);
    const float* b1row = b1 + (size_t)g * DEMB;
    int start = offsets[g], end = offsets[g + 1];

    for (int idx = start + (int)threadIdx.x; idx < end; idx += (int)blockDim.x) {
        int f = sorted[idx];
        float x0 = coords[2 * f + 0];
        float x1 = coords[2 * f + 1];
        int bin = lcg[f];
        int col = (int)((unsigned)bin % (unsigned)gene_n);
        const float* w2row = w2 + (size_t)genes_oi[col] * DEMB;
        float sum = frag_contrib(x0, x1, wrow, b1row, w2row, fr);
        atomicAdd(&out[bin], sum);
    }
}

// ---------------------------------------------------------------------------
// Fallback (no workspace): one thread per fragment, non-uniform gene
// ---------------------------------------------------------------------------
__global__ __launch_bounds__(256) void frag_naive_k(
    const float* __restrict__ coords, const float* __restrict__ w1,
    const float* __restrict__ b1, const float* __restrict__ w2,
    const int* __restrict__ gm, const int* __restrict__ lcg,
    const int* __restrict__ genes_oi, float* __restrict__ out,
    int gene_n, int n_frag)
{
    __shared__ float fr[NF];
    fill_freq(fr);
    __syncthreads();

    int f = blockIdx.x * blockDim.x + threadIdx.x;
    if (f >= n_frag) return;
    int g = gm[f];
    const float* wrow  = w1 + (size_t)g * (DSINE * DEMB);
    const float* b1row = b1 + (size_t)g * DEMB;
    float x0 = coords[2 * f + 0];
    float x1 = coords[2 * f + 1];
    int bin = lcg[f];
    int col = (int)((unsigned)bin % (unsigned)gene_n);
    const float* w2row = w2 + (size_t)genes_oi[col] * DEMB;
    float sum = frag_contrib(x0, x1, wrow, b1row, w2row, fr);
    atomicAdd(&out[bin], sum);
}

// ---------------------------------------------------------------------------
extern "C" void kernel_launch(void* const* d_in, const int* in_sizes, int n_in,
                              void* d_out, int out_size, void* d_ws, size_t ws_size,
                              hipStream_t stream)
{
    const float* coords   = (const float*)d_in[0];
    const float* w1       = (const float*)d_in[1];
    const float* b1       = (const float*)d_in[2];
    const float* w2       = (const float*)d_in[3];
    const float* b2       = (const float*)d_in[4];
    const int*   gm       = (const int*)d_in[5];
    const int*   lcg      = (const int*)d_in[6];
    const int*   genes_oi = (const int*)d_in[7];

    int n_frag  = in_sizes[5];
    int n_genes = in_sizes[4];
    int gene_n  = in_sizes[7];
    int total   = out_size;
    float* out  = (float*)d_out;

    // workspace layout: counts[n_genes] | offsets[n_genes+1] | cursor[n_genes] | sorted[n_frag]
    size_t need = ((size_t)n_genes * 2 + (size_t)(n_genes + 1) + (size_t)n_frag) * sizeof(int);
    int* counts  = (int*)d_ws;
    int* offsets = counts + n_genes;
    int* cursor  = offsets + (n_genes + 1);
    int* sorted  = cursor + n_genes;

    const int tpb = 256;
    prep_k<<<(total + tpb - 1) / tpb, tpb, 0, stream>>>(out, b2, genes_oi, gene_n, total,
                                                        counts, n_genes);

    bool use_sorted = (ws_size >= need) && (n_genes <= 512);
    if (use_sorted) {
        hist_k<<<(n_frag + tpb - 1) / tpb, tpb, 0, stream>>>(gm, counts, n_frag);
        scan_k<<<1, 512, 0, stream>>>(counts, offsets, cursor, n_genes);
        scatter_k<<<(n_frag + tpb - 1) / tpb, tpb, 0, stream>>>(gm, cursor, sorted, n_frag);
        frag_sorted_k<<<n_genes, 256, 0, stream>>>(coords, w1, b1, w2, lcg, genes_oi,
                                                   sorted, offsets, out, gene_n);
    } else {
        frag_naive_k<<<(n_frag + tpb - 1) / tpb, tpb, 0, stream>>>(coords, w1, b1, w2, gm, lcg,
                                                                   genes_oi, out, gene_n, n_frag);
    }
}

// Round 2
// 49.265 us; speedup vs baseline: 3.3569x; 3.3569x over previous
//
#include <hip/hip_runtime.h>
#include <hip/hip_bf16.h>
#include <math.h>

#define NF    50            // n_frequencies
#define DSINE (4 * NF)      // 200
#define DEMB  10            // embedding dim

#define SORT_TPB 256
#define FPT      16
#define CHUNK    (SORT_TPB * FPT)   // 4096 fragments per sort block

// ---------------------------------------------------------------------------
// Fill LDS table of base frequency / (2*pi):  base_i = 1000^(-2(i+1)/NF)
// ---------------------------------------------------------------------------
__device__ __forceinline__ void fill_freq(float* fr) {
    int tid = threadIdx.x;
    if (tid < NF) {
        float ex = (-2.0f * (float)(tid + 1) / (float)NF) * 9.965784284662087f; // log2(1000)
        fr[tid] = exp2f(ex) * 0.15915494309189535f;  // base/(2*pi): v_sin takes revolutions
    }
}

// ---------------------------------------------------------------------------
// Per-fragment contribution: sigma(emb @ w1[g] + b1[g]) . w2row
// ---------------------------------------------------------------------------
__device__ __forceinline__ float frag_contrib(
    float x0, float x1,
    const float* __restrict__ wrow,    // w1 + g*DSINE*DEMB (wave-uniform)
    const float* __restrict__ b1row,   // b1 + g*DEMB       (wave-uniform)
    const float* __restrict__ w2row,   // w2 + genes_oi[col]*DEMB
    const float* __restrict__ fr)
{
    float h[DEMB];
#pragma unroll
    for (int d = 0; d < DEMB; ++d) h[d] = b1row[d];

#pragma unroll 2
    for (int i = 0; i < NF; ++i) {
        float fv = fr[i];
        // reduce to [-0.5, 0.5] revolutions; v_sin/v_cos take revolutions
        float r0 = x0 * fv; r0 -= rintf(r0);
        float r1 = x1 * fv; r1 -= rintf(r1);
        float s0 = __builtin_amdgcn_sinf(r0);
        float c0 = __builtin_amdgcn_cosf(r0);
        float s1 = __builtin_amdgcn_sinf(r1);
        float c1 = __builtin_amdgcn_cosf(r1);
        // emb layout: s = coord*2*NF + 2*i (+1 for the pi/2-shift = cos slot)
        const float* wa = wrow + (2 * i) * DEMB;                 // coord 0
        const float* wb = wrow + (2 * NF + 2 * i) * DEMB;        // coord 1
#pragma unroll
        for (int d = 0; d < DEMB; ++d) {
            h[d] += s0 * wa[d];
            h[d] += c0 * wa[DEMB + d];
            h[d] += s1 * wb[d];
            h[d] += c1 * wb[DEMB + d];
        }
    }

    float sum = 0.0f;
#pragma unroll
    for (int d = 0; d < DEMB; ++d) {
        float sg = 1.0f / (1.0f + __expf(-h[d]));
        sum += sg * w2row[d];
    }
    return sum;
}

// ---------------------------------------------------------------------------
// Kernel 0: init out with broadcast b2, zero gene histogram
// ---------------------------------------------------------------------------
__global__ void prep_k(float* __restrict__ out, const float* __restrict__ b2,
                       const int* __restrict__ genes_oi, int gene_n, int total,
                       int* __restrict__ counts, int n_genes)
{
    int i = blockIdx.x * blockDim.x + threadIdx.x;
    if (i < total) {
        int col = (int)((unsigned)i % (unsigned)gene_n);
        out[i] = b2[genes_oi[col]];
    }
    if (i < n_genes) counts[i] = 0;
}

// ---------------------------------------------------------------------------
// Kernel 1: histogram of genemapping — LDS-aggregated per block
// ---------------------------------------------------------------------------
__global__ __launch_bounds__(SORT_TPB) void hist2_k(
    const int* __restrict__ gm, int* __restrict__ counts, int n_frag, int n_genes)
{
    __shared__ int lcnt[512];
    for (int t = threadIdx.x; t < n_genes; t += SORT_TPB) lcnt[t] = 0;
    __syncthreads();
    int base = blockIdx.x * CHUNK;
#pragma unroll
    for (int j = 0; j < FPT; ++j) {
        int f = base + j * SORT_TPB + (int)threadIdx.x;
        if (f < n_frag) atomicAdd(&lcnt[gm[f]], 1);
    }
    __syncthreads();
    for (int t = threadIdx.x; t < n_genes; t += SORT_TPB) {
        int c = lcnt[t];
        if (c) atomicAdd(&counts[t], c);
    }
}

// ---------------------------------------------------------------------------
// Kernel 2: exclusive scan (single block, n_genes <= 512)
// ---------------------------------------------------------------------------
__global__ void scan_k(const int* __restrict__ counts, int* __restrict__ offsets,
                       int* __restrict__ cursor, int n)
{
    __shared__ int buf[512];
    int tid = threadIdx.x;
    int v = (tid < n) ? counts[tid] : 0;
    buf[tid] = v;
    __syncthreads();
    for (int d = 1; d < 512; d <<= 1) {
        int t = (tid >= d) ? buf[tid - d] : 0;
        __syncthreads();
        buf[tid] += t;
        __syncthreads();
    }
    if (tid < n) {
        int incl = buf[tid];
        offsets[tid + 1] = incl;
        cursor[tid] = incl - v;   // exclusive
    }
    if (tid == 0) offsets[0] = 0;
}

// ---------------------------------------------------------------------------
// Kernel 3: scatter fragment ids into gene-sorted order.
// Two-level: LDS atomics assign local ranks; <=n_genes returning global
// atomics per block reserve the base slots (49 blocks -> ~24.5k global
// atomics instead of 200k).
// ---------------------------------------------------------------------------
__global__ __launch_bounds__(SORT_TPB) void scatter2_k(
    const int* __restrict__ gm, int* __restrict__ cursor,
    int* __restrict__ sorted, int n_frag, int n_genes)
{
    __shared__ int lcnt[512];
    __shared__ int lbase[512];
    for (int t = threadIdx.x; t < n_genes; t += SORT_TPB) lcnt[t] = 0;
    __syncthreads();

    int base = blockIdx.x * CHUNK;
    int g[FPT];
    int lr[FPT];
#pragma unroll
    for (int j = 0; j < FPT; ++j) {
        int f = base + j * SORT_TPB + (int)threadIdx.x;
        if (f < n_frag) {
            g[j]  = gm[f];
            lr[j] = atomicAdd(&lcnt[g[j]], 1);   // LDS atomic: fast rank
        } else {
            g[j] = -1;
        }
    }
    __syncthreads();
    for (int t = threadIdx.x; t < n_genes; t += SORT_TPB) {
        int c = lcnt[t];
        lbase[t] = c ? atomicAdd(&cursor[t], c) : 0;
    }
    __syncthreads();
#pragma unroll
    for (int j = 0; j < FPT; ++j) {
        if (g[j] >= 0) {
            int f = base + j * SORT_TPB + (int)threadIdx.x;
            sorted[lbase[g[j]] + lr[j]] = f;
        }
    }
}

// ---------------------------------------------------------------------------
// Kernel 4: main — SPLIT blocks per gene, wave-uniform w1/b1 access
// ---------------------------------------------------------------------------
#define SPLIT 2
__global__ __launch_bounds__(256) void frag_sorted_k(
    const float* __restrict__ coords, const float* __restrict__ w1,
    const float* __restrict__ b1, const float* __restrict__ w2,
    const int* __restrict__ lcg, const int* __restrict__ genes_oi,
    const int* __restrict__ sorted, const int* __restrict__ offsets,
    float* __restrict__ out, int gene_n)
{
    __shared__ float fr[NF];
    fill_freq(fr);
    __syncthreads();

    int g    = blockIdx.x / SPLIT;     // uniform gene per block
    int part = blockIdx.x % SPLIT;
    const float* wrow  = w1 + (size_t)g * (DSINE * DEMB);
    const float* b1row = b1 + (size_t)g * DEMB;
    int s0 = offsets[g], e0 = offsets[g + 1];
    int n = e0 - s0;
    int half = (n + SPLIT - 1) / SPLIT;
    int start = s0 + part * half;
    int end = (start + half < e0) ? (start + half) : e0;

    for (int idx = start + (int)threadIdx.x; idx < end; idx += 256) {
        int f = sorted[idx];
        float x0 = coords[2 * f + 0];
        float x1 = coords[2 * f + 1];
        int bin = lcg[f];
        int col = (int)((unsigned)bin % (unsigned)gene_n);
        const float* w2row = w2 + (size_t)genes_oi[col] * DEMB;
        float sum = frag_contrib(x0, x1, wrow, b1row, w2row, fr);
        atomicAdd(&out[bin], sum);
    }
}

// ---------------------------------------------------------------------------
// Fallback (no workspace): one thread per fragment, non-uniform gene
// ---------------------------------------------------------------------------
__global__ __launch_bounds__(256) void frag_naive_k(
    const float* __restrict__ coords, const float* __restrict__ w1,
    const float* __restrict__ b1, const float* __restrict__ w2,
    const int* __restrict__ gm, const int* __restrict__ lcg,
    const int* __restrict__ genes_oi, float* __restrict__ out,
    int gene_n, int n_frag)
{
    __shared__ float fr[NF];
    fill_freq(fr);
    __syncthreads();

    int f = blockIdx.x * blockDim.x + threadIdx.x;
    if (f >= n_frag) return;
    int g = gm[f];
    const float* wrow  = w1 + (size_t)g * (DSINE * DEMB);
    const float* b1row = b1 + (size_t)g * DEMB;
    float x0 = coords[2 * f + 0];
    float x1 = coords[2 * f + 1];
    int bin = lcg[f];
    int col = (int)((unsigned)bin % (unsigned)gene_n);
    const float* w2row = w2 + (size_t)genes_oi[col] * DEMB;
    float sum = frag_contrib(x0, x1, wrow, b1row, w2row, fr);
    atomicAdd(&out[bin], sum);
}

// ---------------------------------------------------------------------------
extern "C" void kernel_launch(void* const* d_in, const int* in_sizes, int n_in,
                              void* d_out, int out_size, void* d_ws, size_t ws_size,
                              hipStream_t stream)
{
    const float* coords   = (const float*)d_in[0];
    const float* w1       = (const float*)d_in[1];
    const float* b1       = (const float*)d_in[2];
    const float* w2       = (const float*)d_in[3];
    const float* b2       = (const float*)d_in[4];
    const int*   gm       = (const int*)d_in[5];
    const int*   lcg      = (const int*)d_in[6];
    const int*   genes_oi = (const int*)d_in[7];

    int n_frag  = in_sizes[5];
    int n_genes = in_sizes[4];
    int gene_n  = in_sizes[7];
    int total   = out_size;
    float* out  = (float*)d_out;

    // workspace layout: counts[n_genes] | offsets[n_genes+1] | cursor[n_genes] | sorted[n_frag]
    size_t need = ((size_t)n_genes * 2 + (size_t)(n_genes + 1) + (size_t)n_frag) * sizeof(int);
    int* counts  = (int*)d_ws;
    int* offsets = counts + n_genes;
    int* cursor  = offsets + (n_genes + 1);
    int* sorted  = cursor + n_genes;

    const int tpb = 256;
    prep_k<<<(total + tpb - 1) / tpb, tpb, 0, stream>>>(out, b2, genes_oi, gene_n, total,
                                                        counts, n_genes);

    bool use_sorted = (ws_size >= need) && (n_genes <= 512);
    if (use_sorted) {
        int sort_blocks = (n_frag + CHUNK - 1) / CHUNK;
        hist2_k<<<sort_blocks, SORT_TPB, 0, stream>>>(gm, counts, n_frag, n_genes);
        scan_k<<<1, 512, 0, stream>>>(counts, offsets, cursor, n_genes);
        scatter2_k<<<sort_blocks, SORT_TPB, 0, stream>>>(gm, cursor, sorted, n_frag, n_genes);
        frag_sorted_k<<<n_genes * SPLIT, 256, 0, stream>>>(coords, w1, b1, w2, lcg, genes_oi,
                                                           sorted, offsets, out, gene_n);
    } else {
        frag_naive_k<<<(n_frag + tpb - 1) / tpb, tpb, 0, stream>>>(coords, w1, b1, w2, gm, lcg,
                                                                   genes_oi, out, gene_n, n_frag);
    }
}